// Round 6
// baseline (497.864 us; speedup 1.0000x reference)
//
#include <hip/hip_runtime.h>

// LightGCN on MI355X (gfx950).
// N = 150000 nodes, d = 64, nnz = 6.4M edges, 3 layers, 4096 queries.
// Pipeline: fixed-capacity row-bin scatter (ILP-batched, 8 edges/thread/batch)
// -> per-bin LDS sort to per-row (start,end) -> wave-per-row gather SpMM on a
// bf16 table with f32 accumulators.

constexpr int D = 64;
constexpr int RB = 64;            // rows per bin
constexpr int BCAP = 4096;        // fixed region capacity per bin (lambda=2731, +26 sigma)
constexpr int CHUNK = 8192;       // edges per binning workgroup (32/thread)

__device__ __forceinline__ float bflo(unsigned u) { return __uint_as_float(u << 16); }
__device__ __forceinline__ float bfhi(unsigned u) { return __uint_as_float(u & 0xFFFF0000u); }
__device__ __forceinline__ float bf1(ushort u) { return __uint_as_float((unsigned)u << 16); }
__device__ __forceinline__ unsigned bfpack(float f0, float f1) {
    unsigned u0 = __float_as_uint(f0), u1 = __float_as_uint(f1);
    u0 = (u0 + 0x7FFFu + ((u0 >> 16) & 1u)) >> 16;   // round-to-nearest-even
    u1 = (u1 + 0x7FFFu + ((u1 >> 16) & 1u)) >> 16;
    return u0 | (u1 << 16);
}

// ---- pack e0 = [user_emb; item_emb] into bf16 table ----
__global__ __launch_bounds__(256) void pack_e0(const float4* __restrict__ u4,
                                               const float4* __restrict__ i4,
                                               uint2* __restrict__ ebf2,
                                               long long nU4, long long total4) {
    long long t = (long long)blockIdx.x * blockDim.x + threadIdx.x;
    if (t >= total4) return;
    float4 v = (t < nU4) ? u4[t] : i4[t - nU4];
    ebf2[t] = make_uint2(bfpack(v.x, v.y), bfpack(v.z, v.w));
}

// ---- init query accumulators with layer-0 embeddings (f32 inputs, exact) ----
__global__ __launch_bounds__(64) void gather_init(const float* __restrict__ ue,
                                                  const float* __restrict__ ie,
                                                  const int* __restrict__ uidx,
                                                  const int* __restrict__ iidx,
                                                  float* __restrict__ accU,
                                                  float* __restrict__ accI) {
    int j = blockIdx.x;
    int lane = threadIdx.x;
    accU[(size_t)j * D + lane] = ue[(size_t)uidx[j] * D + lane];
    accI[(size_t)j * D + lane] = ie[(size_t)iidx[j] * D + lane];
}

// ---- scatter into fixed-capacity bin regions; ILP-batched (latency-bound fix) ----
// packed .x: bits[23:18] = row-in-bin, bits[17:0] = col ; .y = weight bits
__global__ __launch_bounds__(256) void bin_scatter(const int2* __restrict__ idx2,
                                                   const float* __restrict__ adj,
                                                   int* __restrict__ cursor,
                                                   int2* __restrict__ binned,
                                                   long long nnz, int NB) {
    extern __shared__ int sh[];
    int* h = sh;            // [NB] local histogram, then local cursor
    int* rbase = sh + NB;   // [NB] bulk-reserved global base
    const int tid = threadIdx.x;
    for (int i = tid; i < NB; i += 256) h[i] = 0;
    __syncthreads();
    const long long base = (long long)blockIdx.x * CHUNK;
    const bool full = (base + CHUNK <= nnz);

    // ---- histogram phase ----
    if (full) {
        #pragma unroll
        for (int b4 = 0; b4 < 4; ++b4) {
            long long g0 = base + b4 * 2048 + tid * 8;     // 8 consecutive edges
            int4 m0 = *(const int4*)(idx2 + g0);           // {r,c,r,c}
            int4 m1 = *(const int4*)(idx2 + g0 + 2);
            int4 m2 = *(const int4*)(idx2 + g0 + 4);
            int4 m3 = *(const int4*)(idx2 + g0 + 6);
            atomicAdd(&h[m0.x >> 6], 1); atomicAdd(&h[m0.z >> 6], 1);
            atomicAdd(&h[m1.x >> 6], 1); atomicAdd(&h[m1.z >> 6], 1);
            atomicAdd(&h[m2.x >> 6], 1); atomicAdd(&h[m2.z >> 6], 1);
            atomicAdd(&h[m3.x >> 6], 1); atomicAdd(&h[m3.z >> 6], 1);
        }
    } else {
        for (int i = tid; i < CHUNK; i += 256) {
            long long g = base + i;
            if (g < nnz) atomicAdd(&h[idx2[g].x >> 6], 1);
        }
    }
    __syncthreads();

    // ---- bulk reservation ----
    for (int i = tid; i < NB; i += 256) {
        int v = h[i];
        rbase[i] = v ? atomicAdd(&cursor[i], v) : 0;
        h[i] = 0;   // reuse as local cursor
    }
    __syncthreads();

    // ---- scatter phase ----
    auto emit = [&](int row, int col, float w) {
        int b = row >> 6;
        int pos = rbase[b] + atomicAdd(&h[b], 1);
        if (pos < BCAP)   // statistically never taken; memory-safety clamp
            binned[(size_t)b * BCAP + pos] =
                make_int2(((row & 63) << 18) | col, __float_as_int(w));
    };
    if (full) {
        #pragma unroll
        for (int b4 = 0; b4 < 4; ++b4) {
            long long g0 = base + b4 * 2048 + tid * 8;
            int4 m0 = *(const int4*)(idx2 + g0);
            int4 m1 = *(const int4*)(idx2 + g0 + 2);
            int4 m2 = *(const int4*)(idx2 + g0 + 4);
            int4 m3 = *(const int4*)(idx2 + g0 + 6);
            float4 w0 = *(const float4*)(adj + g0);
            float4 w1 = *(const float4*)(adj + g0 + 4);
            emit(m0.x, m0.y, w0.x); emit(m0.z, m0.w, w0.y);
            emit(m1.x, m1.y, w0.z); emit(m1.z, m1.w, w0.w);
            emit(m2.x, m2.y, w1.x); emit(m2.z, m2.w, w1.y);
            emit(m3.x, m3.y, w1.z); emit(m3.z, m3.w, w1.w);
        }
    } else {
        for (int i = tid; i < CHUNK; i += 256) {
            long long g = base + i;
            if (g < nnz) {
                int2 rc = idx2[g];
                emit(rc.x, rc.y, adj[g]);
            }
        }
    }
}

// ---- per-bin LDS sort: bin region -> row-sorted region + per-row (start,end) ----
__global__ __launch_bounds__(256) void bin_sort(int2* __restrict__ binned,
                                                const int* __restrict__ cursor,
                                                int2* __restrict__ row_se,
                                                int N) {
    __shared__ int2 buf[BCAP];    // 32 KB
    __shared__ int h[RB];
    __shared__ int lcur[RB];
    int b = blockIdx.x, tid = threadIdx.x;
    size_t bbase = (size_t)b * BCAP;
    int len = cursor[b];
    if (len > BCAP) len = BCAP;
    for (int i = tid; i < len; i += 256) buf[i] = binned[bbase + i];
    if (tid < RB) h[tid] = 0;
    __syncthreads();
    for (int i = tid; i < len; i += 256) atomicAdd(&h[(buf[i].x >> 18) & 63], 1);
    __syncthreads();
    if (tid < RB) {                          // wave 0: 64-wide exclusive scan
        int v = h[tid];
        int incl = v;
        #pragma unroll
        for (int off = 1; off < RB; off <<= 1) {
            int t = __shfl_up(incl, off, 64);
            if (tid >= off) incl += t;
        }
        int excl = incl - v;
        lcur[tid] = excl;
        int row = b * RB + tid;
        if (row < N) row_se[row] = make_int2((int)bbase + excl, (int)bbase + excl + v);
    }
    __syncthreads();
    for (int i = tid; i < len; i += 256) {
        int2 p = buf[i];
        int rb = (p.x >> 18) & 63;
        int pos = atomicAdd(&lcur[rb], 1);
        binned[bbase + pos] = make_int2(p.x & 0x3FFFF, p.y);   // strip rb
    }
}

// ---- SpMM: wave per row, 8 edges in flight, bf16 gathers, f32 accumulate ----
__global__ __launch_bounds__(256) void spmm_bf16(const int2* __restrict__ csr,
                                                 const int2* __restrict__ row_se,
                                                 const ushort* __restrict__ ebf,
                                                 ushort* __restrict__ ebf_next,
                                                 int N) {
    int tid = threadIdx.x;
    int row = blockIdx.x * 4 + (tid >> 6);
    if (row >= N) return;
    int lane = tid & 63, eg = lane >> 3, sub = lane & 7;
    int2 se = row_se[row];
    int s = se.x, len = se.y - se.x;
    float a0 = 0, a1 = 0, a2 = 0, a3 = 0, a4 = 0, a5 = 0, a6 = 0, a7 = 0;
    #pragma unroll 2
    for (int i = eg; i < len; i += 8) {
        int2 cw = csr[s + i];
        float w = __int_as_float(cw.y);
        uint4 v = *(const uint4*)(ebf + (size_t)cw.x * D + sub * 8);   // 16B = 8 bf16
        a0 += w * bflo(v.x); a1 += w * bfhi(v.x);
        a2 += w * bflo(v.y); a3 += w * bfhi(v.y);
        a4 += w * bflo(v.z); a5 += w * bfhi(v.z);
        a6 += w * bflo(v.w); a7 += w * bfhi(v.w);
    }
    #pragma unroll
    for (int off = 8; off < 64; off <<= 1) {   // reduce across the 8 edge groups
        a0 += __shfl_xor(a0, off, 64); a1 += __shfl_xor(a1, off, 64);
        a2 += __shfl_xor(a2, off, 64); a3 += __shfl_xor(a3, off, 64);
        a4 += __shfl_xor(a4, off, 64); a5 += __shfl_xor(a5, off, 64);
        a6 += __shfl_xor(a6, off, 64); a7 += __shfl_xor(a7, off, 64);
    }
    if (eg == 0) {
        uint4 pk = make_uint4(bfpack(a0, a1), bfpack(a2, a3), bfpack(a4, a5), bfpack(a6, a7));
        *(uint4*)(ebf_next + (size_t)row * D + sub * 8) = pk;
    }
}

// ---- fold one layer's gathered rows (bf16 table) into the f32 accumulators ----
__global__ __launch_bounds__(64) void gather_acc(const ushort* __restrict__ e,
                                                 const int* __restrict__ uidx,
                                                 const int* __restrict__ iidx,
                                                 float* __restrict__ accU,
                                                 float* __restrict__ accI,
                                                 int n_users) {
    int j = blockIdx.x;
    int lane = threadIdx.x;
    accU[(size_t)j * D + lane] += bf1(e[(size_t)uidx[j] * D + lane]);
    accI[(size_t)j * D + lane] += bf1(e[((size_t)n_users + iidx[j]) * D + lane]);
}

// ---- final dot: out[j] = dot(accU[j]/4, accI[j]/4) ----
__global__ __launch_bounds__(64) void final_dot(const float* __restrict__ accU,
                                                const float* __restrict__ accI,
                                                float* __restrict__ out) {
    int j = blockIdx.x;
    int lane = threadIdx.x;
    float p = accU[(size_t)j * D + lane] * accI[(size_t)j * D + lane];
    #pragma unroll
    for (int off = 32; off > 0; off >>= 1) p += __shfl_down(p, off);
    if (lane == 0) out[j] = p * (1.0f / 16.0f);
}

extern "C" void kernel_launch(void* const* d_in, const int* in_sizes, int n_in,
                              void* d_out, int out_size, void* d_ws, size_t ws_size,
                              hipStream_t stream) {
    const float* user_emb = (const float*)d_in[0];
    const float* item_emb = (const float*)d_in[1];
    const float* adj_data = (const float*)d_in[2];
    const int* adj_indices = (const int*)d_in[3];
    const int* user_idx = (const int*)d_in[4];
    const int* item_idx = (const int*)d_in[5];
    float* out = (float*)d_out;

    const int n_users = in_sizes[0] / D;
    const int n_items = in_sizes[1] / D;
    const long long nnz = in_sizes[2];
    const int N = n_users + n_items;
    const int nq = in_sizes[4];
    const int NB = (N + RB - 1) / RB;

    // ---- workspace layout (~118 MB) ----
    char* p = (char*)d_ws;
    auto alloc = [&](size_t bytes) { char* q = p; p += (bytes + 255) & ~(size_t)255; return q; };
    ushort* ebf0 = (ushort*)alloc((size_t)N * D * sizeof(ushort));   // bf16 table ping
    ushort* ebf1 = (ushort*)alloc((size_t)N * D * sizeof(ushort));   // bf16 table pong
    float* accU = (float*)alloc((size_t)nq * D * sizeof(float));
    float* accI = (float*)alloc((size_t)nq * D * sizeof(float));
    int2* binned = (int2*)alloc((size_t)NB * BCAP * sizeof(int2));   // fixed bin regions
    int* cursor = (int*)alloc((size_t)NB * sizeof(int));
    int2* row_se = (int2*)alloc((size_t)N * sizeof(int2));

    const int2* idx2 = (const int2*)adj_indices;
    const int nChunks = (int)((nnz + CHUNK - 1) / CHUNK);
    const size_t sh_bytes = (size_t)2 * NB * sizeof(int);   // 18.75 KB -> 8 wg/CU

    // ---- e0 (bf16) = concat(user_emb, item_emb) ----
    {
        long long total4 = (long long)N * (D / 4);
        long long nU4 = (long long)n_users * (D / 4);
        pack_e0<<<(int)((total4 + 255) / 256), 256, 0, stream>>>(
            (const float4*)user_emb, (const float4*)item_emb, (uint2*)ebf0, nU4, total4);
    }
    gather_init<<<nq, 64, 0, stream>>>(user_emb, item_emb, user_idx, item_idx, accU, accI);

    // ---- build row-sorted bin regions ----
    hipMemsetAsync(cursor, 0, (size_t)NB * sizeof(int), stream);
    bin_scatter<<<nChunks, 256, sh_bytes, stream>>>(idx2, adj_data, cursor, binned, nnz, NB);
    bin_sort<<<NB, 256, 0, stream>>>(binned, cursor, row_se, N);

    // ---- 3 layers of SpMM + query-row accumulation ----
    ushort* ebc = ebf0;
    ushort* ebn = ebf1;
    const int spmm_blocks = (N + 3) / 4;
    for (int layer = 0; layer < 3; ++layer) {
        spmm_bf16<<<spmm_blocks, 256, 0, stream>>>(binned, row_se, ebc, ebn, N);
        gather_acc<<<nq, 64, 0, stream>>>(ebn, user_idx, item_idx, accU, accI, n_users);
        ushort* t = ebc; ebc = ebn; ebn = t;
    }

    final_dot<<<nq, 64, 0, stream>>>(accU, accI, out);
}

// Round 7
// 383.619 us; speedup vs baseline: 1.2978x; 1.2978x over previous
//
#include <hip/hip_runtime.h>

// LightGCN on MI355X (gfx950).
// N = 150000 nodes, d = 64, nnz = 6.4M edges, 3 layers, 4096 queries.
// Pipeline: fixed-capacity row-bin scatter (16-deep ILP) -> per-bin LDS sort ->
// wave-per-row gather SpMM on bf16 table (layers 1-2 full, layer 3 fused to
// query rows only, accumulated in f32).

constexpr int D = 64;
constexpr int RB = 64;            // rows per bin
constexpr int BCAP = 4096;        // fixed region capacity per bin (lambda=2731, +26 sigma)
constexpr int CHUNK = 8192;       // edges per binning workgroup (32/thread)

__device__ __forceinline__ float bflo(unsigned u) { return __uint_as_float(u << 16); }
__device__ __forceinline__ float bfhi(unsigned u) { return __uint_as_float(u & 0xFFFF0000u); }
__device__ __forceinline__ float bf1(ushort u) { return __uint_as_float((unsigned)u << 16); }
__device__ __forceinline__ unsigned bfpack(float f0, float f1) {
    unsigned u0 = __float_as_uint(f0), u1 = __float_as_uint(f1);
    u0 = (u0 + 0x7FFFu + ((u0 >> 16) & 1u)) >> 16;   // round-to-nearest-even
    u1 = (u1 + 0x7FFFu + ((u1 >> 16) & 1u)) >> 16;
    return u0 | (u1 << 16);
}

// ---- pack e0 = [user_emb; item_emb] into bf16 table ----
__global__ __launch_bounds__(256) void pack_e0(const float4* __restrict__ u4,
                                               const float4* __restrict__ i4,
                                               uint2* __restrict__ ebf2,
                                               long long nU4, long long total4) {
    long long t = (long long)blockIdx.x * blockDim.x + threadIdx.x;
    if (t >= total4) return;
    float4 v = (t < nU4) ? u4[t] : i4[t - nU4];
    ebf2[t] = make_uint2(bfpack(v.x, v.y), bfpack(v.z, v.w));
}

// ---- init query accumulators with layer-0 embeddings (f32 inputs, exact) ----
__global__ __launch_bounds__(64) void gather_init(const float* __restrict__ ue,
                                                  const float* __restrict__ ie,
                                                  const int* __restrict__ uidx,
                                                  const int* __restrict__ iidx,
                                                  float* __restrict__ accU,
                                                  float* __restrict__ accI) {
    int j = blockIdx.x;
    int lane = threadIdx.x;
    accU[(size_t)j * D + lane] = ue[(size_t)uidx[j] * D + lane];
    accI[(size_t)j * D + lane] = ie[(size_t)iidx[j] * D + lane];
}

// ---- scatter into fixed-capacity bin regions; 16 edges in flight per thread ----
// packed .x: bits[23:18] = row-in-bin, bits[17:0] = col ; .y = weight bits
__global__ __launch_bounds__(256) void bin_scatter(const int2* __restrict__ idx2,
                                                   const float* __restrict__ adj,
                                                   int* __restrict__ cursor,
                                                   int2* __restrict__ binned,
                                                   long long nnz, int NB) {
    extern __shared__ int sh[];
    int* h = sh;            // [NB] local histogram, then local cursor
    int* rbase = sh + NB;   // [NB] bulk-reserved global base
    const int tid = threadIdx.x;
    for (int i = tid; i < NB; i += 256) h[i] = 0;
    __syncthreads();
    const long long base = (long long)blockIdx.x * CHUNK;
    const bool full = (base + CHUNK <= nnz);

    // ---- histogram phase ----
    if (full) {
        #pragma unroll
        for (int bb = 0; bb < 2; ++bb) {
            long long g0 = base + bb * 4096 + tid * 16;   // 16 consecutive edges
            int4 m[8];
            #pragma unroll
            for (int k = 0; k < 8; ++k) m[k] = *(const int4*)(idx2 + g0 + 2 * k);
            #pragma unroll
            for (int k = 0; k < 8; ++k) {
                atomicAdd(&h[m[k].x >> 6], 1);
                atomicAdd(&h[m[k].z >> 6], 1);
            }
        }
    } else {
        for (int i = tid; i < CHUNK; i += 256) {
            long long g = base + i;
            if (g < nnz) atomicAdd(&h[idx2[g].x >> 6], 1);
        }
    }
    __syncthreads();

    // ---- bulk reservation ----
    for (int i = tid; i < NB; i += 256) {
        int v = h[i];
        rbase[i] = v ? atomicAdd(&cursor[i], v) : 0;
        h[i] = 0;   // reuse as local cursor
    }
    __syncthreads();

    // ---- scatter phase ----
    auto emit = [&](int row, int col, float w) {
        int b = row >> 6;
        int pos = rbase[b] + atomicAdd(&h[b], 1);
        if (pos < BCAP)   // statistically never taken; memory-safety clamp
            binned[(size_t)b * BCAP + pos] =
                make_int2(((row & 63) << 18) | col, __float_as_int(w));
    };
    if (full) {
        #pragma unroll
        for (int bb = 0; bb < 2; ++bb) {
            long long g0 = base + bb * 4096 + tid * 16;
            int4 m[8];
            float4 w[4];
            #pragma unroll
            for (int k = 0; k < 8; ++k) m[k] = *(const int4*)(idx2 + g0 + 2 * k);
            #pragma unroll
            for (int k = 0; k < 4; ++k) w[k] = *(const float4*)(adj + g0 + 4 * k);
            #pragma unroll
            for (int k = 0; k < 8; ++k) {
                float wa = (k & 1) ? ((k & 2) ? w[k >> 1].z : w[k >> 1].x)
                                   : ((k & 2) ? w[k >> 1].z : w[k >> 1].x);
                (void)wa;
            }
            // emit all 16 (weights: edge k2 = g0+k2 -> w[k2/4] component k2%4)
            #pragma unroll
            for (int k = 0; k < 8; ++k) {
                int e0i = 2 * k, e1i = 2 * k + 1;
                float w0 = ((const float*)w)[e0i];
                float w1 = ((const float*)w)[e1i];
                emit(m[k].x, m[k].y, w0);
                emit(m[k].z, m[k].w, w1);
            }
        }
    } else {
        for (int i = tid; i < CHUNK; i += 256) {
            long long g = base + i;
            if (g < nnz) {
                int2 rc = idx2[g];
                emit(rc.x, rc.y, adj[g]);
            }
        }
    }
}

// ---- per-bin LDS sort: bin region -> row-sorted region + per-row (start,end) ----
__global__ __launch_bounds__(256) void bin_sort(int2* __restrict__ binned,
                                                const int* __restrict__ cursor,
                                                int2* __restrict__ row_se,
                                                int N) {
    __shared__ int2 buf[BCAP];    // 32 KB
    __shared__ int h[RB];
    __shared__ int lcur[RB];
    int b = blockIdx.x, tid = threadIdx.x;
    size_t bbase = (size_t)b * BCAP;
    int len = cursor[b];
    if (len > BCAP) len = BCAP;
    for (int i = tid; i < len; i += 256) buf[i] = binned[bbase + i];
    if (tid < RB) h[tid] = 0;
    __syncthreads();
    for (int i = tid; i < len; i += 256) atomicAdd(&h[(buf[i].x >> 18) & 63], 1);
    __syncthreads();
    if (tid < RB) {                          // wave 0: 64-wide exclusive scan
        int v = h[tid];
        int incl = v;
        #pragma unroll
        for (int off = 1; off < RB; off <<= 1) {
            int t = __shfl_up(incl, off, 64);
            if (tid >= off) incl += t;
        }
        int excl = incl - v;
        lcur[tid] = excl;
        int row = b * RB + tid;
        if (row < N) row_se[row] = make_int2((int)bbase + excl, (int)bbase + excl + v);
    }
    __syncthreads();
    for (int i = tid; i < len; i += 256) {
        int2 p = buf[i];
        int rb = (p.x >> 18) & 63;
        int pos = atomicAdd(&lcur[rb], 1);
        binned[bbase + pos] = make_int2(p.x & 0x3FFFF, p.y);   // strip rb
    }
}

// ---- SpMM (full): wave per row, 8 edges in flight, bf16 gathers, f32 acc ----
__global__ __launch_bounds__(256) void spmm_bf16(const int2* __restrict__ csr,
                                                 const int2* __restrict__ row_se,
                                                 const ushort* __restrict__ ebf,
                                                 ushort* __restrict__ ebf_next,
                                                 int N) {
    int tid = threadIdx.x;
    int row = blockIdx.x * 4 + (tid >> 6);
    if (row >= N) return;
    int lane = tid & 63, eg = lane >> 3, sub = lane & 7;
    int2 se = row_se[row];
    int s = se.x, len = se.y - se.x;
    float a0 = 0, a1 = 0, a2 = 0, a3 = 0, a4 = 0, a5 = 0, a6 = 0, a7 = 0;
    #pragma unroll 2
    for (int i = eg; i < len; i += 8) {
        int2 cw = csr[s + i];
        float w = __int_as_float(cw.y);
        uint4 v = *(const uint4*)(ebf + (size_t)cw.x * D + sub * 8);   // 16B = 8 bf16
        a0 += w * bflo(v.x); a1 += w * bfhi(v.x);
        a2 += w * bflo(v.y); a3 += w * bfhi(v.y);
        a4 += w * bflo(v.z); a5 += w * bfhi(v.z);
        a6 += w * bflo(v.w); a7 += w * bfhi(v.w);
    }
    #pragma unroll
    for (int off = 8; off < 64; off <<= 1) {
        a0 += __shfl_xor(a0, off, 64); a1 += __shfl_xor(a1, off, 64);
        a2 += __shfl_xor(a2, off, 64); a3 += __shfl_xor(a3, off, 64);
        a4 += __shfl_xor(a4, off, 64); a5 += __shfl_xor(a5, off, 64);
        a6 += __shfl_xor(a6, off, 64); a7 += __shfl_xor(a7, off, 64);
    }
    if (eg == 0) {
        uint4 pk = make_uint4(bfpack(a0, a1), bfpack(a2, a3), bfpack(a4, a5), bfpack(a6, a7));
        *(uint4*)(ebf_next + (size_t)row * D + sub * 8) = pk;
    }
}

// ---- SpMM (layer 3, fused): query rows only, accumulate f32 into accU/accI ----
__global__ __launch_bounds__(256) void spmm_query(const int2* __restrict__ csr,
                                                  const int2* __restrict__ row_se,
                                                  const ushort* __restrict__ ebf,
                                                  const int* __restrict__ uidx,
                                                  const int* __restrict__ iidx,
                                                  float* __restrict__ accU,
                                                  float* __restrict__ accI,
                                                  int n_users, int nq) {
    int tid = threadIdx.x;
    int vq = blockIdx.x * 4 + (tid >> 6);
    if (vq >= 2 * nq) return;
    int lane = tid & 63, eg = lane >> 3, sub = lane & 7;
    bool isU = vq < nq;
    int j = isU ? vq : vq - nq;
    int row = isU ? uidx[j] : n_users + iidx[j];
    int2 se = row_se[row];
    int s = se.x, len = se.y - se.x;
    float a0 = 0, a1 = 0, a2 = 0, a3 = 0, a4 = 0, a5 = 0, a6 = 0, a7 = 0;
    #pragma unroll 2
    for (int i = eg; i < len; i += 8) {
        int2 cw = csr[s + i];
        float w = __int_as_float(cw.y);
        uint4 v = *(const uint4*)(ebf + (size_t)cw.x * D + sub * 8);
        a0 += w * bflo(v.x); a1 += w * bfhi(v.x);
        a2 += w * bflo(v.y); a3 += w * bfhi(v.y);
        a4 += w * bflo(v.z); a5 += w * bfhi(v.z);
        a6 += w * bflo(v.w); a7 += w * bfhi(v.w);
    }
    #pragma unroll
    for (int off = 8; off < 64; off <<= 1) {
        a0 += __shfl_xor(a0, off, 64); a1 += __shfl_xor(a1, off, 64);
        a2 += __shfl_xor(a2, off, 64); a3 += __shfl_xor(a3, off, 64);
        a4 += __shfl_xor(a4, off, 64); a5 += __shfl_xor(a5, off, 64);
        a6 += __shfl_xor(a6, off, 64); a7 += __shfl_xor(a7, off, 64);
    }
    if (eg == 0) {
        float* acc = (isU ? accU : accI) + (size_t)j * D + sub * 8;
        float4* f4 = (float4*)acc;
        float4 c0 = f4[0], c1 = f4[1];
        f4[0] = make_float4(c0.x + a0, c0.y + a1, c0.z + a2, c0.w + a3);
        f4[1] = make_float4(c1.x + a4, c1.y + a5, c1.z + a6, c1.w + a7);
    }
}

// ---- fold one layer's gathered rows (bf16 table) into the f32 accumulators ----
__global__ __launch_bounds__(64) void gather_acc(const ushort* __restrict__ e,
                                                 const int* __restrict__ uidx,
                                                 const int* __restrict__ iidx,
                                                 float* __restrict__ accU,
                                                 float* __restrict__ accI,
                                                 int n_users) {
    int j = blockIdx.x;
    int lane = threadIdx.x;
    accU[(size_t)j * D + lane] += bf1(e[(size_t)uidx[j] * D + lane]);
    accI[(size_t)j * D + lane] += bf1(e[((size_t)n_users + iidx[j]) * D + lane]);
}

// ---- final dot: out[j] = dot(accU[j]/4, accI[j]/4) ----
__global__ __launch_bounds__(64) void final_dot(const float* __restrict__ accU,
                                                const float* __restrict__ accI,
                                                float* __restrict__ out) {
    int j = blockIdx.x;
    int lane = threadIdx.x;
    float p = accU[(size_t)j * D + lane] * accI[(size_t)j * D + lane];
    #pragma unroll
    for (int off = 32; off > 0; off >>= 1) p += __shfl_down(p, off);
    if (lane == 0) out[j] = p * (1.0f / 16.0f);
}

extern "C" void kernel_launch(void* const* d_in, const int* in_sizes, int n_in,
                              void* d_out, int out_size, void* d_ws, size_t ws_size,
                              hipStream_t stream) {
    const float* user_emb = (const float*)d_in[0];
    const float* item_emb = (const float*)d_in[1];
    const float* adj_data = (const float*)d_in[2];
    const int* adj_indices = (const int*)d_in[3];
    const int* user_idx = (const int*)d_in[4];
    const int* item_idx = (const int*)d_in[5];
    float* out = (float*)d_out;

    const int n_users = in_sizes[0] / D;
    const int n_items = in_sizes[1] / D;
    const long long nnz = in_sizes[2];
    const int N = n_users + n_items;
    const int nq = in_sizes[4];
    const int NB = (N + RB - 1) / RB;

    // ---- workspace layout (~118 MB) ----
    char* p = (char*)d_ws;
    auto alloc = [&](size_t bytes) { char* q = p; p += (bytes + 255) & ~(size_t)255; return q; };
    ushort* ebf0 = (ushort*)alloc((size_t)N * D * sizeof(ushort));   // bf16 table ping
    ushort* ebf1 = (ushort*)alloc((size_t)N * D * sizeof(ushort));   // bf16 table pong
    float* accU = (float*)alloc((size_t)nq * D * sizeof(float));
    float* accI = (float*)alloc((size_t)nq * D * sizeof(float));
    int2* binned = (int2*)alloc((size_t)NB * BCAP * sizeof(int2));   // fixed bin regions
    int* cursor = (int*)alloc((size_t)NB * sizeof(int));
    int2* row_se = (int2*)alloc((size_t)N * sizeof(int2));

    const int2* idx2 = (const int2*)adj_indices;
    const int nChunks = (int)((nnz + CHUNK - 1) / CHUNK);
    const size_t sh_bytes = (size_t)2 * NB * sizeof(int);

    // ---- e0 (bf16) = concat(user_emb, item_emb) ----
    {
        long long total4 = (long long)N * (D / 4);
        long long nU4 = (long long)n_users * (D / 4);
        pack_e0<<<(int)((total4 + 255) / 256), 256, 0, stream>>>(
            (const float4*)user_emb, (const float4*)item_emb, (uint2*)ebf0, nU4, total4);
    }
    gather_init<<<nq, 64, 0, stream>>>(user_emb, item_emb, user_idx, item_idx, accU, accI);

    // ---- build row-sorted bin regions ----
    hipMemsetAsync(cursor, 0, (size_t)NB * sizeof(int), stream);
    bin_scatter<<<nChunks, 256, sh_bytes, stream>>>(idx2, adj_data, cursor, binned, nnz, NB);
    bin_sort<<<NB, 256, 0, stream>>>(binned, cursor, row_se, N);

    // ---- layers 1-2: full SpMM + query-row accumulation ----
    ushort* ebc = ebf0;
    ushort* ebn = ebf1;
    const int spmm_blocks = (N + 3) / 4;
    for (int layer = 0; layer < 2; ++layer) {
        spmm_bf16<<<spmm_blocks, 256, 0, stream>>>(binned, row_se, ebc, ebn, N);
        gather_acc<<<nq, 64, 0, stream>>>(ebn, user_idx, item_idx, accU, accI, n_users);
        ushort* t = ebc; ebc = ebn; ebn = t;
    }

    // ---- layer 3 fused: SpMM restricted to the 8192 query rows, f32 accumulate ----
    spmm_query<<<(2 * nq + 3) / 4, 256, 0, stream>>>(binned, row_se, ebc, user_idx, item_idx,
                                                     accU, accI, n_users, nq);

    final_dot<<<nq, 64, 0, stream>>>(accU, accI, out);
}